// Round 14
// baseline (86.226 us; speedup 1.0000x reference)
//
#include <hip/hip_runtime.h>

// Chamfer via MFMA, round 14: round-13 fusion with the two regressions fixed.
//  - launch_bounds (256,4): 128-VGPR budget (round-12 diag_imm regime) so the
//    4 q-tile accumulators schedule without serialization. (Round 13's (256,6)
//    capped at 85 VGPR and gave back the fusion gains.)
//  - NJ=8, JCHUNK=1024 (32 KB LDS): grid 1024 = exactly 4 blocks/CU, one pass,
//    half the prep redundancy of round 13.
//  - loss_part on 256 blocks (full chip) instead of 64.
// Structure (validated absmax 0 rounds 3-13): fused prep (A-frags in regs,
// B-rep in LDS from raw floats), swapped-operand MFMA (lane=query, regs=16
// targets), in-register max3 tree, direct-store per-jc slices, no atomics.
//   A(q) = [qh(3), ql(3), qh(3), hq_h, hq_l,  1,  1, 0,0,0]
//   B(t) = [th(3), th(3), tl(3),  -1,  -1, -ht_h, -ht_l, 0,0,0]

#define NPTS    8192
#define BATCH   4
#define NJ      8
#define JCHUNK  1024               // targets per block: 32 tiles, 32 KB LDS
#define JTILES  32
#define NSLOTS  (2 * BATCH * NPTS) // 65536

typedef __attribute__((ext_vector_type(8))) short short8v;
typedef __attribute__((ext_vector_type(16))) float f32x16;

__device__ __forceinline__ unsigned short f2bf(float x) {   // RNE bf16
  unsigned u = __float_as_uint(x);
  unsigned r = u + 0x7FFFu + ((u >> 16) & 1u);
  return (unsigned short)(r >> 16);
}
__device__ __forceinline__ float bf2f(unsigned short b) {
  return __uint_as_float((unsigned)b << 16);
}

__device__ __forceinline__ float tree17(const f32x16& c, float m) {
  float t0 = fmaxf(fmaxf(c[0],  c[1]),  c[2]);    // v_max3_f32 x8 (optimal)
  float t1 = fmaxf(fmaxf(c[3],  c[4]),  c[5]);
  float t2 = fmaxf(fmaxf(c[6],  c[7]),  c[8]);
  float t3 = fmaxf(fmaxf(c[9],  c[10]), c[11]);
  float t4 = fmaxf(fmaxf(c[12], c[13]), c[14]);
  float u0 = fmaxf(fmaxf(t0, t1), t2);
  float u1 = fmaxf(fmaxf(t3, t4), c[15]);
  return fmaxf(fmaxf(u0, u1), m);
}

// Build this lane's A-fragment (k-half h) for the query at src (3 floats).
__device__ __forceinline__ short8v make_afrag(const float* __restrict__ src, int h) {
  float x = src[0], y = src[1], z = src[2];
  unsigned short xh = f2bf(x), yh = f2bf(y), zh = f2bf(z);
  unsigned short xl = f2bf(x - bf2f(xh)), yl = f2bf(y - bf2f(yh)),
                 zl = f2bf(z - bf2f(zh));
  float hn = 0.5f * (x * x + y * y + z * z);
  unsigned short hh = f2bf(hn), hl = f2bf(hn - bf2f(hh));
  const unsigned short one = 0x3F80u;
  unsigned short lo[8] = {xh, yh, zh, xl, yl, zl, xh, yh};
  unsigned short hi[8] = {zh, hh, hl, one, one, 0, 0, 0};
  short8v r;
  #pragma unroll
  for (int i = 0; i < 8; ++i) r[i] = (short)(h ? hi[i] : lo[i]);
  return r;
}

// grid = 2(dir) x 4(b) x 16(ig: 512 queries) x 8(jc) = 1024 blocks x 4 waves.
// Wave owns 4 query-tiles (128 queries); block builds 1024-target rep in LDS
// from raw floats and loops 32 target tiles.
__global__ __launch_bounds__(256, 4) void chamfer_main(
    const float* __restrict__ c1, const float* __restrict__ c2,
    float* __restrict__ rowbuf) {
  __shared__ __align__(16) unsigned short sB[JCHUNK * 16];  // 32 KB

  int bid = blockIdx.x;
  int jc  = bid & 7;
  int ig  = (bid >> 3) & 15;
  int b   = (bid >> 7) & 3;
  int dir = bid >> 9;

  const float* Q = dir ? c2 : c1;   // queries (raw floats)
  const float* T = dir ? c1 : c2;   // targets (raw floats)

  int t = threadIdx.x, wave = t >> 6, lane = t & 63;
  int p = lane & 31, h = lane >> 5;

  // ---- build B-rep for 1024 targets directly in LDS (4 per thread) ----
  const unsigned short negone = 0xBF80u;
  #pragma unroll
  for (int s = 0; s < 4; ++s) {
    int j = t + s * 256;
    const float* src = T + ((size_t)b * NPTS + jc * JCHUNK + j) * 3;
    float x = src[0], y = src[1], z = src[2];
    unsigned short xh = f2bf(x), yh = f2bf(y), zh = f2bf(z);
    unsigned short xl = f2bf(x - bf2f(xh)), yl = f2bf(y - bf2f(yh)),
                   zl = f2bf(z - bf2f(zh));
    float hn = 0.5f * (x * x + y * y + z * z);
    unsigned short hh = f2bf(hn), hl = f2bf(hn - bf2f(hh));
    unsigned short vb[16] = {xh, yh, zh, xh, yh, zh, xl, yl, zl,
                             negone, negone,
                             (unsigned short)(hh ^ 0x8000u),
                             (unsigned short)(hl ^ 0x8000u), 0, 0, 0};
    // layout: byte = jt*1024 + khalf*512 + point*16
    char* dst = (char*)sB + (j >> 5) * 1024 + (j & 31) * 16;
    *(uint4*)dst         = *(const uint4*)&vb[0];
    *(uint4*)(dst + 512) = *(const uint4*)&vb[8];
  }

  // ---- build A-fragments (4 query tiles) in registers ----
  int q0 = ig * 512 + wave * 128;
  const float* qb = Q + ((size_t)b * NPTS + q0 + p) * 3;
  short8v aq0 = make_afrag(qb,          h);
  short8v aq1 = make_afrag(qb + 32 * 3, h);
  short8v aq2 = make_afrag(qb + 64 * 3, h);
  short8v aq3 = make_afrag(qb + 96 * 3, h);

  f32x16 zero;
  #pragma unroll
  for (int i = 0; i < 16; ++i) zero[i] = 0.0f;
  float m0 = -3.4e38f, m1 = -3.4e38f, m2 = -3.4e38f, m3 = -3.4e38f;

  __syncthreads();

  const char* spBase = (const char*)sB + h * 512 + p * 16;  // conflict-free

  #pragma unroll 4
  for (int jt = 0; jt < JTILES; ++jt) {
    short8v bt = *(const short8v*)(const void*)(spBase + jt * 1024);
    // swapped operands: rows(regs)=targets, cols(lanes)=queries
    f32x16 c0 = __builtin_amdgcn_mfma_f32_32x32x16_bf16(bt, aq0, zero, 0, 0, 0);
    f32x16 c1 = __builtin_amdgcn_mfma_f32_32x32x16_bf16(bt, aq1, zero, 0, 0, 0);
    f32x16 c2 = __builtin_amdgcn_mfma_f32_32x32x16_bf16(bt, aq2, zero, 0, 0, 0);
    f32x16 c3 = __builtin_amdgcn_mfma_f32_32x32x16_bf16(bt, aq3, zero, 0, 0, 0);
    m0 = tree17(c0, m0);   // in-lane: 16 targets for THIS lane's query
    m1 = tree17(c1, m1);
    m2 = tree17(c2, m2);
    m3 = tree17(c3, m3);
  }

  // lane L and L^32 hold the two target-halves of the same query
  m0 = fmaxf(m0, __shfl_xor(m0, 32, 64));
  m1 = fmaxf(m1, __shfl_xor(m1, 32, 64));
  m2 = fmaxf(m2, __shfl_xor(m2, 32, 64));
  m3 = fmaxf(m3, __shfl_xor(m3, 32, 64));

  // direct store into this jc's private slice — no atomics, no init
  if (lane < 32) {
    float* rb = rowbuf + (size_t)jc * NSLOTS +
                ((size_t)dir * BATCH + b) * NPTS + q0;
    rb[p]      = m0;
    rb[32 + p] = m1;
    rb[64 + p] = m2;
    rb[96 + p] = m3;
  }
}

// 256 blocks x 256 threads: each thread folds 1 slot over the 8 jc slices.
__global__ __launch_bounds__(256) void loss_part(
    const float* __restrict__ rowbuf, float* __restrict__ partials) {
  int slot = blockIdx.x * 256 + threadIdx.x;   // 0..65535
  float m = -3.4e38f;
  #pragma unroll
  for (int j = 0; j < NJ; ++j)
    m = fmaxf(m, rowbuf[(size_t)j * NSLOTS + slot]);
  float s = -2.0f * m;   // min squared distance for this slot
  #pragma unroll
  for (int off = 32; off > 0; off >>= 1) s += __shfl_down(s, off, 64);
  __shared__ float wsum[4];
  if ((threadIdx.x & 63) == 0) wsum[threadIdx.x >> 6] = s;
  __syncthreads();
  if (threadIdx.x == 0)
    partials[blockIdx.x] = (wsum[0] + wsum[1]) + (wsum[2] + wsum[3]);
}

__global__ __launch_bounds__(256) void loss_fin(
    const float* __restrict__ partials, float* __restrict__ out) {
  float s = partials[threadIdx.x];   // 256 partials
  #pragma unroll
  for (int off = 32; off > 0; off >>= 1) s += __shfl_down(s, off, 64);
  __shared__ float wsum[4];
  if ((threadIdx.x & 63) == 0) wsum[threadIdx.x >> 6] = s;
  __syncthreads();
  if (threadIdx.x == 0) out[0] = (wsum[0] + wsum[1]) + (wsum[2] + wsum[3]);
}

extern "C" void kernel_launch(void* const* d_in, const int* in_sizes, int n_in,
                              void* d_out, int out_size, void* d_ws, size_t ws_size,
                              hipStream_t stream) {
  const float* c1 = (const float*)d_in[0];
  const float* c2 = (const float*)d_in[1];
  float* out = (float*)d_out;

  char* ws = (char*)d_ws;
  float* rowbuf = (float*)ws;                                  // 8 x 65536 f32 = 2 MB
  float* partials = (float*)(ws + (size_t)NJ * NSLOTS * 4);    // 256 f32

  chamfer_main<<<2 * BATCH * 16 * NJ, 256, 0, stream>>>(c1, c2, rowbuf);
  loss_part<<<256, 256, 0, stream>>>(rowbuf, partials);
  loss_fin<<<1, 256, 0, stream>>>(partials, out);
}

// Round 15
// 27.009 us; speedup vs baseline: 3.1925x; 3.1925x over previous
//
#include <hip/hip_runtime.h>

// Chamfer via MFMA, round 15: diag_imm loop (the only measured-clean codegen:
// 14.9us/pass, VGPR 52, no scratch) + fused prep + atomic-free stores.
// Round-14 lesson: unroll>1 over 4-MFMA groups -> 16 f32x16 in flight ->
// spill catastrophe (400 MB scratch traffic, 84us). So: #pragma unroll 1,
// bt/btn explicit prefetch, trees consumed immediately.
// No address-taken locals (vector-select afrag, packed uint4 B-rep writes).
// Swapped-operand MFMA (lane=query, regs=16 targets) + in-reg max3 tree.
// bf16 hi/lo rep (validated absmax 0, rounds 3-14):
//   A(q) = [qh(3), ql(3), qh(3), hq_h, hq_l,  1,  1, 0,0,0]
//   B(t) = [th(3), th(3), tl(3),  -1,  -1, -ht_h, -ht_l, 0,0,0]

#define NPTS    8192
#define BATCH   4
#define NJ      8
#define JCHUNK  1024               // targets per block: 32 tiles
#define JTILES  32
#define NSLOTS  (2 * BATCH * NPTS) // 65536

typedef __attribute__((ext_vector_type(8))) short short8v;
typedef __attribute__((ext_vector_type(16))) float f32x16;

__device__ __forceinline__ unsigned short f2bf(float x) {   // RNE bf16
  unsigned u = __float_as_uint(x);
  unsigned r = u + 0x7FFFu + ((u >> 16) & 1u);
  return (unsigned short)(r >> 16);
}
__device__ __forceinline__ float bf2f(unsigned short b) {
  return __uint_as_float((unsigned)b << 16);
}
__device__ __forceinline__ unsigned pack2(unsigned short a, unsigned short b) {
  return (unsigned)a | ((unsigned)b << 16);
}

__device__ __forceinline__ float tree17(const f32x16& c, float m) {
  float t0 = fmaxf(fmaxf(c[0],  c[1]),  c[2]);    // v_max3_f32 x8
  float t1 = fmaxf(fmaxf(c[3],  c[4]),  c[5]);
  float t2 = fmaxf(fmaxf(c[6],  c[7]),  c[8]);
  float t3 = fmaxf(fmaxf(c[9],  c[10]), c[11]);
  float t4 = fmaxf(fmaxf(c[12], c[13]), c[14]);
  float u0 = fmaxf(fmaxf(t0, t1), t2);
  float u1 = fmaxf(fmaxf(t3, t4), c[15]);
  return fmaxf(fmaxf(u0, u1), m);
}

// Lane's A-fragment (k-half h) for query at src; whole-vector select, no arrays.
__device__ __forceinline__ short8v make_afrag(const float* __restrict__ src, int h) {
  float x = src[0], y = src[1], z = src[2];
  unsigned short xh = f2bf(x), yh = f2bf(y), zh = f2bf(z);
  unsigned short xl = f2bf(x - bf2f(xh)), yl = f2bf(y - bf2f(yh)),
                 zl = f2bf(z - bf2f(zh));
  float hn = 0.5f * (x * x + y * y + z * z);
  unsigned short hh = f2bf(hn), hl = f2bf(hn - bf2f(hh));
  const short one = (short)0x3F80;
  short8v vlo, vhi;
  vlo[0] = (short)xh; vlo[1] = (short)yh; vlo[2] = (short)zh; vlo[3] = (short)xl;
  vlo[4] = (short)yl; vlo[5] = (short)zl; vlo[6] = (short)xh; vlo[7] = (short)yh;
  vhi[0] = (short)zh; vhi[1] = (short)hh; vhi[2] = (short)hl; vhi[3] = one;
  vhi[4] = one;       vhi[5] = 0;         vhi[6] = 0;         vhi[7] = 0;
  return h ? vhi : vlo;
}

// grid = 2(dir) x 4(b) x 16(ig: 512 queries) x 8(jc) = 1024 blocks x 4 waves.
__global__ __launch_bounds__(256, 4) void chamfer_main(
    const float* __restrict__ c1, const float* __restrict__ c2,
    float* __restrict__ rowbuf) {
  __shared__ __align__(16) unsigned short sB[(JCHUNK + 32) * 16];  // 33 KB (pad: btn prefetch)

  int bid = blockIdx.x;
  int jc  = bid & 7;
  int ig  = (bid >> 3) & 15;
  int b   = (bid >> 7) & 3;
  int dir = bid >> 9;

  const float* Q = dir ? c2 : c1;   // queries (raw floats)
  const float* T = dir ? c1 : c2;   // targets (raw floats)

  int t = threadIdx.x, wave = t >> 6, lane = t & 63;
  int p = lane & 31, h = lane >> 5;

  // ---- build B-rep for 1024 targets directly in LDS (4 per thread) ----
  const unsigned short negone = 0xBF80u;
  #pragma unroll
  for (int s = 0; s < 4; ++s) {
    int j = t + s * 256;
    const float* src = T + ((size_t)b * NPTS + jc * JCHUNK + j) * 3;
    float x = src[0], y = src[1], z = src[2];
    unsigned short xh = f2bf(x), yh = f2bf(y), zh = f2bf(z);
    unsigned short xl = f2bf(x - bf2f(xh)), yl = f2bf(y - bf2f(yh)),
                   zl = f2bf(z - bf2f(zh));
    float hn = 0.5f * (x * x + y * y + z * z);
    unsigned short hh = f2bf(hn), hl = f2bf(hn - bf2f(hh));
    unsigned short nh = hh ^ 0x8000u, nl = hl ^ 0x8000u;
    // slots 0..7: {xh,yh,zh,xh,yh,zh,xl,yl}; 8..15: {zl,-1,-1,nh,nl,0,0,0}
    uint4 w0 = make_uint4(pack2(xh, yh), pack2(zh, xh), pack2(yh, zh), pack2(xl, yl));
    uint4 w1 = make_uint4(pack2(zl, negone), pack2(negone, nh), pack2(nl, 0), 0u);
    // layout: byte = jt*1024 + khalf*512 + point*16
    char* dst = (char*)sB + (j >> 5) * 1024 + (j & 31) * 16;
    *(uint4*)dst         = w0;
    *(uint4*)(dst + 512) = w1;
  }

  // ---- A-fragments (4 query tiles) in registers ----
  int q0 = ig * 512 + wave * 128;
  const float* qb = Q + ((size_t)b * NPTS + q0 + p) * 3;
  short8v aq0 = make_afrag(qb,          h);
  short8v aq1 = make_afrag(qb + 32 * 3, h);
  short8v aq2 = make_afrag(qb + 64 * 3, h);
  short8v aq3 = make_afrag(qb + 96 * 3, h);

  f32x16 zero;
  #pragma unroll
  for (int i = 0; i < 16; ++i) zero[i] = 0.0f;
  float m0 = -3.4e38f, m1 = -3.4e38f, m2 = -3.4e38f, m3 = -3.4e38f;

  __syncthreads();

  // ---- diag_imm loop: unroll 1, bt/btn prefetch, immediate consumption ----
  const char* sp = (const char*)sB + h * 512 + p * 16;   // conflict-free
  short8v bt = *(const short8v*)(const void*)(sp);
  #pragma unroll 1
  for (int jt = 0; jt < JTILES; ++jt) {
    short8v btn = *(const short8v*)(const void*)(sp + (size_t)(jt + 1) * 1024);
    f32x16 c0 = __builtin_amdgcn_mfma_f32_32x32x16_bf16(bt, aq0, zero, 0, 0, 0);
    f32x16 c1 = __builtin_amdgcn_mfma_f32_32x32x16_bf16(bt, aq1, zero, 0, 0, 0);
    f32x16 c2 = __builtin_amdgcn_mfma_f32_32x32x16_bf16(bt, aq2, zero, 0, 0, 0);
    f32x16 c3 = __builtin_amdgcn_mfma_f32_32x32x16_bf16(bt, aq3, zero, 0, 0, 0);
    m0 = tree17(c0, m0);   // in-lane: 16 targets for THIS lane's query
    m1 = tree17(c1, m1);
    m2 = tree17(c2, m2);
    m3 = tree17(c3, m3);
    bt = btn;
  }

  // lane L and L^32 hold the two target-halves of the same query
  m0 = fmaxf(m0, __shfl_xor(m0, 32, 64));
  m1 = fmaxf(m1, __shfl_xor(m1, 32, 64));
  m2 = fmaxf(m2, __shfl_xor(m2, 32, 64));
  m3 = fmaxf(m3, __shfl_xor(m3, 32, 64));

  // direct store into this jc's private slice — no atomics, no init
  if (lane < 32) {
    float* rb = rowbuf + (size_t)jc * NSLOTS +
                ((size_t)dir * BATCH + b) * NPTS + q0;
    rb[p]      = m0;
    rb[32 + p] = m1;
    rb[64 + p] = m2;
    rb[96 + p] = m3;
  }
}

// 256 blocks x 256 threads: each thread folds 1 slot over the 8 jc slices.
__global__ __launch_bounds__(256) void loss_part(
    const float* __restrict__ rowbuf, float* __restrict__ partials) {
  int slot = blockIdx.x * 256 + threadIdx.x;   // 0..65535
  float m = -3.4e38f;
  #pragma unroll
  for (int j = 0; j < NJ; ++j)
    m = fmaxf(m, rowbuf[(size_t)j * NSLOTS + slot]);
  float s = -2.0f * m;   // min squared distance for this slot
  #pragma unroll
  for (int off = 32; off > 0; off >>= 1) s += __shfl_down(s, off, 64);
  __shared__ float wsum[4];
  if ((threadIdx.x & 63) == 0) wsum[threadIdx.x >> 6] = s;
  __syncthreads();
  if (threadIdx.x == 0)
    partials[blockIdx.x] = (wsum[0] + wsum[1]) + (wsum[2] + wsum[3]);
}

__global__ __launch_bounds__(256) void loss_fin(
    const float* __restrict__ partials, float* __restrict__ out) {
  float s = partials[threadIdx.x];   // 256 partials
  #pragma unroll
  for (int off = 32; off > 0; off >>= 1) s += __shfl_down(s, off, 64);
  __shared__ float wsum[4];
  if ((threadIdx.x & 63) == 0) wsum[threadIdx.x >> 6] = s;
  __syncthreads();
  if (threadIdx.x == 0) out[0] = (wsum[0] + wsum[1]) + (wsum[2] + wsum[3]);
}

extern "C" void kernel_launch(void* const* d_in, const int* in_sizes, int n_in,
                              void* d_out, int out_size, void* d_ws, size_t ws_size,
                              hipStream_t stream) {
  const float* c1 = (const float*)d_in[0];
  const float* c2 = (const float*)d_in[1];
  float* out = (float*)d_out;

  char* ws = (char*)d_ws;
  float* rowbuf = (float*)ws;                                  // 8 x 65536 f32 = 2 MB
  float* partials = (float*)(ws + (size_t)NJ * NSLOTS * 4);    // 256 f32

  chamfer_main<<<2 * BATCH * 16 * NJ, 256, 0, stream>>>(c1, c2, rowbuf);
  loss_part<<<256, 256, 0, stream>>>(rowbuf, partials);
  loss_fin<<<1, 256, 0, stream>>>(partials, out);
}